// Round 1
// baseline (1118.164 us; speedup 1.0000x reference)
//
#include <hip/hip_runtime.h>
#include <hip/hip_bf16.h>

#define N_NODES   50000
#define N_EDGES   800000
#define D         256
#define N_LAYERS  3
#define N_GRAPHS  64
#define LN_EPS    1e-5f

// ---------------------------------------------------------------------------
// degree histogram
__global__ void k_indeg(const int* __restrict__ dst, int* __restrict__ indeg) {
    int e = blockIdx.x * blockDim.x + threadIdx.x;
    if (e < N_EDGES) atomicAdd(&indeg[dst[e]], 1);
}

// dinv = rsqrt(indeg + 1)
__global__ void k_dinv(const int* __restrict__ indeg, float* __restrict__ dinv) {
    int n = blockIdx.x * blockDim.x + threadIdx.x;
    if (n < N_NODES) dinv[n] = rsqrtf((float)(indeg[n] + 1));
}

// single-block exclusive scan of indeg -> offsets (and cursor copy)
__global__ void k_scan(const int* __restrict__ indeg, int* __restrict__ offsets,
                       int* __restrict__ cursor) {
    __shared__ int s[1024];
    __shared__ int carry;
    int t = threadIdx.x;
    if (t == 0) carry = 0;
    __syncthreads();
    const int nchunk = (N_NODES + 1023) / 1024;
    for (int c = 0; c < nchunk; ++c) {
        int i = c * 1024 + t;
        int v = (i < N_NODES) ? indeg[i] : 0;
        s[t] = v;
        __syncthreads();
        // Hillis-Steele inclusive scan
        for (int off = 1; off < 1024; off <<= 1) {
            int tv = (t >= off) ? s[t - off] : 0;
            __syncthreads();
            s[t] += tv;
            __syncthreads();
        }
        int excl = s[t] - v;
        if (i < N_NODES) {
            int o = carry + excl;
            offsets[i] = o;
            cursor[i]  = o;
        }
        __syncthreads();
        if (t == 0) carry += s[1023];
        __syncthreads();
    }
}

// scatter edges into CSR slots; pack (src, coef) as int2
__global__ void k_csr_fill(const int* __restrict__ src, const int* __restrict__ dst,
                           const float* __restrict__ dinv, int* __restrict__ cursor,
                           int2* __restrict__ epairs) {
    int e = blockIdx.x * blockDim.x + threadIdx.x;
    if (e >= N_EDGES) return;
    int s = src[e], d = dst[e];
    int pos = atomicAdd(&cursor[d], 1);
    float coef = dinv[s] * dinv[d];
    epairs[pos] = make_int2(s, __float_as_int(coef));
}

// ---------------------------------------------------------------------------
// GEMM: B[M,256] = A[M,256] @ W[256,256]   (fp32, 64-row tile, 8x8 per thread)
__global__ __launch_bounds__(256) void k_gemm(const float* __restrict__ A,
                                              const float* __restrict__ W,
                                              float* __restrict__ Bo) {
    __shared__ float xs[64 * 256];            // 64 KB
    int t = threadIdx.x;
    int brow = blockIdx.x * 64;

    const float4* A4 = (const float4*)A;
    float4* xs4 = (float4*)xs;
#pragma unroll
    for (int j = 0; j < 16; ++j) {
        int f = j * 256 + t;                  // float4 index in 64x64-f4 tile
        int row = brow + (f >> 6);
        float4 v;
        if (row < N_NODES) v = A4[(size_t)brow * 64 + f];
        else { v.x = v.y = v.z = v.w = 0.f; }
        xs4[f] = v;
    }
    __syncthreads();

    int cg = t & 31, rg = t >> 5;
    int c0 = cg * 8, r0 = rg * 8;
    float acc[8][8];
#pragma unroll
    for (int r = 0; r < 8; ++r)
#pragma unroll
        for (int c = 0; c < 8; ++c) acc[r][c] = 0.f;

    const float4* W4 = (const float4*)W;
    for (int k0 = 0; k0 < 256; k0 += 4) {
        float wreg[4][8];
#pragma unroll
        for (int kk = 0; kk < 4; ++kk) {
            int base = (((k0 + kk) << 8) + c0) >> 2;
            float4 wa = W4[base];
            float4 wb = W4[base + 1];
            wreg[kk][0] = wa.x; wreg[kk][1] = wa.y; wreg[kk][2] = wa.z; wreg[kk][3] = wa.w;
            wreg[kk][4] = wb.x; wreg[kk][5] = wb.y; wreg[kk][6] = wb.z; wreg[kk][7] = wb.w;
        }
#pragma unroll
        for (int r = 0; r < 8; ++r) {
            float4 xv = xs4[(r0 + r) * 64 + (k0 >> 2)];
            float xk[4] = {xv.x, xv.y, xv.z, xv.w};
#pragma unroll
            for (int kk = 0; kk < 4; ++kk)
#pragma unroll
                for (int c = 0; c < 8; ++c)
                    acc[r][c] = fmaf(xk[kk], wreg[kk][c], acc[r][c]);
        }
    }

    float4* B4 = (float4*)Bo;
#pragma unroll
    for (int r = 0; r < 8; ++r) {
        int row = brow + r0 + r;
        if (row < N_NODES) {
            float4 o0, o1;
            o0.x = acc[r][0]; o0.y = acc[r][1]; o0.z = acc[r][2]; o0.w = acc[r][3];
            o1.x = acc[r][4]; o1.y = acc[r][5]; o1.z = acc[r][6]; o1.w = acc[r][7];
            B4[(size_t)row * 64 + (c0 >> 2)]     = o0;
            B4[(size_t)row * 64 + (c0 >> 2) + 1] = o1;
        }
    }
}

// ---------------------------------------------------------------------------
// fused gather-aggregate + self-loop + bias + LayerNorm + ReLU
// one wave (64 lanes) per node; lane owns 4 dims (float4)
__global__ __launch_bounds__(256) void k_agg_ln(const float* __restrict__ h1,
                                                const int* __restrict__ offsets,
                                                const int* __restrict__ indeg,
                                                const float* __restrict__ dinv,
                                                const int2* __restrict__ epairs,
                                                const float* __restrict__ bias,
                                                const float* __restrict__ gamma,
                                                const float* __restrict__ beta,
                                                float* __restrict__ out) {
    int node = blockIdx.x * 4 + (threadIdx.x >> 6);
    int lane = threadIdx.x & 63;
    if (node >= N_NODES) return;

    const float4* h4 = (const float4*)h1;
    float di = dinv[node];
    float selfc = di * di;

    float4 v = h4[(size_t)node * 64 + lane];
    float4 acc;
    acc.x = v.x * selfc; acc.y = v.y * selfc; acc.z = v.z * selfc; acc.w = v.w * selfc;

    int beg = offsets[node];
    int end = beg + indeg[node];
    for (int i = beg; i < end; ++i) {
        int2 ep = epairs[i];
        float c = __int_as_float(ep.y);
        float4 hv = h4[(size_t)ep.x * 64 + lane];
        acc.x = fmaf(hv.x, c, acc.x);
        acc.y = fmaf(hv.y, c, acc.y);
        acc.z = fmaf(hv.z, c, acc.z);
        acc.w = fmaf(hv.w, c, acc.w);
    }

    const float4* b4 = (const float4*)bias;
    float4 bv = b4[lane];
    acc.x += bv.x; acc.y += bv.y; acc.z += bv.z; acc.w += bv.w;

    // LayerNorm over 256 dims (wave reduction)
    float part = acc.x + acc.y + acc.z + acc.w;
#pragma unroll
    for (int m = 32; m >= 1; m >>= 1) part += __shfl_xor(part, m);
    float mu = part * (1.0f / 256.0f);

    float dx = acc.x - mu, dy = acc.y - mu, dz = acc.z - mu, dw = acc.w - mu;
    float p2 = dx * dx + dy * dy + dz * dz + dw * dw;
#pragma unroll
    for (int m = 32; m >= 1; m >>= 1) p2 += __shfl_xor(p2, m);
    float var = p2 * (1.0f / 256.0f);
    float rs = rsqrtf(var + LN_EPS);

    const float4* g4 = (const float4*)gamma;
    const float4* be4 = (const float4*)beta;
    float4 gv = g4[lane], bev = be4[lane];
    float4 o;
    o.x = fmaxf(dx * rs * gv.x + bev.x, 0.f);
    o.y = fmaxf(dy * rs * gv.y + bev.y, 0.f);
    o.z = fmaxf(dz * rs * gv.z + bev.z, 0.f);
    o.w = fmaxf(dw * rs * gv.w + bev.w, 0.f);
    ((float4*)out)[(size_t)node * 64 + lane] = o;
}

// ---------------------------------------------------------------------------
// graph counts
__global__ void k_counts(const int* __restrict__ batch, int* __restrict__ counts) {
    int n = blockIdx.x * blockDim.x + threadIdx.x;
    if (n < N_NODES) atomicAdd(&counts[batch[n]], 1);
}

// pooling: block handles 128 contiguous nodes, thread owns one dim,
// flush to atomics only at graph boundaries (batch is sorted)
__global__ __launch_bounds__(256) void k_pool(const float* __restrict__ h,
                                              const int* __restrict__ batch,
                                              float* __restrict__ sums) {
    __shared__ int sb[128];
    int t = threadIdx.x;
    int n0 = blockIdx.x * 128;
    int cnt = N_NODES - n0; if (cnt > 128) cnt = 128;
    if (cnt <= 0) return;
    if (t < cnt) sb[t] = batch[n0 + t];
    __syncthreads();

    float acc = 0.f;
    int g = sb[0];
    for (int i = 0; i < cnt; ++i) {
        int bg = sb[i];
        if (bg != g) {
            atomicAdd(&sums[g * 256 + t], acc);
            acc = 0.f;
            g = bg;
        }
        acc += h[(size_t)(n0 + i) * 256 + t];
    }
    atomicAdd(&sums[g * 256 + t], acc);
}

__global__ void k_finalize(const float* __restrict__ sums, const int* __restrict__ counts,
                           float* __restrict__ out) {
    int idx = blockIdx.x * blockDim.x + threadIdx.x;
    if (idx < N_GRAPHS * 256) {
        float c = (float)counts[idx >> 8];
        out[idx] = sums[idx] / fmaxf(c, 1.f);
    }
}

// ---------------------------------------------------------------------------
extern "C" void kernel_launch(void* const* d_in, const int* in_sizes, int n_in,
                              void* d_out, int out_size, void* d_ws, size_t ws_size,
                              hipStream_t stream) {
    const float* x     = (const float*)d_in[0];
    const int*   ei    = (const int*)d_in[1];
    const int*   batch = (const int*)d_in[2];
    const float* Ws    = (const float*)d_in[3];
    const float* bs    = (const float*)d_in[4];
    const float* gammas= (const float*)d_in[5];
    const float* betas = (const float*)d_in[6];
    float* out = (float*)d_out;

    const int* src = ei;
    const int* dst = ei + N_EDGES;

    // workspace layout (16B-aligned chunks)
    char* p = (char*)d_ws;
    float* bufA   = (float*)p; p += (size_t)N_NODES * D * 4;   // 51.2 MB
    float* bufB   = (float*)p; p += (size_t)N_NODES * D * 4;   // 51.2 MB
    int*   indeg  = (int*)p;   p += (size_t)N_NODES * 4;
    int*   offs   = (int*)p;   p += (size_t)N_NODES * 4;
    int*   cursor = (int*)p;   p += (size_t)N_NODES * 4;
    float* dinv   = (float*)p; p += (size_t)N_NODES * 4;
    int2*  epairs = (int2*)p;  p += (size_t)N_EDGES * 8;
    float* sums   = (float*)p; p += (size_t)N_GRAPHS * D * 4;
    int*   counts = (int*)p;   p += (size_t)N_GRAPHS * 4;

    // ---- graph preprocessing (per call; deterministic) ----
    hipMemsetAsync(indeg, 0, (size_t)N_NODES * 4, stream);
    hipMemsetAsync(sums, 0, (size_t)N_GRAPHS * D * 4, stream);
    hipMemsetAsync(counts, 0, (size_t)N_GRAPHS * 4, stream);

    k_indeg<<<(N_EDGES + 255) / 256, 256, 0, stream>>>(dst, indeg);
    k_dinv<<<(N_NODES + 255) / 256, 256, 0, stream>>>(indeg, dinv);
    k_scan<<<1, 1024, 0, stream>>>(indeg, offs, cursor);
    k_csr_fill<<<(N_EDGES + 255) / 256, 256, 0, stream>>>(src, dst, dinv, cursor, epairs);
    k_counts<<<(N_NODES + 255) / 256, 256, 0, stream>>>(batch, counts);

    // ---- 3 GCN layers ----
    const int gemm_grid = (N_NODES + 63) / 64;
    const int agg_grid  = (N_NODES + 3) / 4;
    for (int l = 0; l < N_LAYERS; ++l) {
        const float* hin = (l == 0) ? x : bufA;
        k_gemm<<<gemm_grid, 256, 0, stream>>>(hin, Ws + (size_t)l * D * D, bufB);
        k_agg_ln<<<agg_grid, 256, 0, stream>>>(bufB, offs, indeg, dinv, epairs,
                                               bs + (size_t)l * D,
                                               gammas + (size_t)l * D,
                                               betas + (size_t)l * D, bufA);
    }

    // ---- global mean pool ----
    k_pool<<<(N_NODES + 127) / 128, 256, 0, stream>>>(bufA, batch, sums);
    k_finalize<<<(N_GRAPHS * 256 + 255) / 256, 256, 0, stream>>>(sums, counts, out);
}

// Round 2
// 611.167 us; speedup vs baseline: 1.8296x; 1.8296x over previous
//
#include <hip/hip_runtime.h>
#include <hip/hip_bf16.h>

#define N_NODES   50000
#define N_EDGES   800000
#define D         256
#define N_LAYERS  3
#define N_GRAPHS  64
#define LN_EPS    1e-5f
#define NB_SCAN   ((N_NODES + 255) / 256)   // 196

typedef __attribute__((ext_vector_type(8))) short bf16x8;
typedef __attribute__((ext_vector_type(4))) float f32x4;

__device__ __forceinline__ unsigned short f2bf(float f) {
    unsigned int u = __float_as_uint(f);
    unsigned int r = (u + 0x7FFFu + ((u >> 16) & 1u)) >> 16;
    return (unsigned short)r;
}
__device__ __forceinline__ float bf2f(unsigned short h) {
    return __uint_as_float(((unsigned int)h) << 16);
}

// ---------------------------------------------------------------------------
// x (fp32) -> bf16
__global__ void k_xtobf(const float* __restrict__ x, unsigned short* __restrict__ xb) {
    int gid = blockIdx.x * blockDim.x + threadIdx.x;      // one per 8 elems
    int base = gid * 8;
    if (base >= N_NODES * D) return;
    const float4* x4 = (const float4*)(x + base);
    float4 a = x4[0], b = x4[1];
    ushort4 lo, hi;
    lo.x = f2bf(a.x); lo.y = f2bf(a.y); lo.z = f2bf(a.z); lo.w = f2bf(a.w);
    hi.x = f2bf(b.x); hi.y = f2bf(b.y); hi.z = f2bf(b.z); hi.w = f2bf(b.w);
    ((ushort4*)(xb + base))[0] = lo;
    ((ushort4*)(xb + base))[1] = hi;
}

// W [l][k][n] fp32 -> Wbt [l][n][k] bf16 (transposed for MFMA B-frag loads)
__global__ void k_wtrans(const float* __restrict__ W, unsigned short* __restrict__ Wbt) {
    int gid = blockIdx.x * blockDim.x + threadIdx.x;
    if (gid >= N_LAYERS * D * D) return;
    int l = gid >> 16;
    int rem = gid & 65535;
    int n = rem >> 8;
    int k = rem & 255;
    Wbt[(size_t)l * D * D + n * D + k] = f2bf(W[(size_t)l * D * D + k * D + n]);
}

// ---------------------------------------------------------------------------
// degree histogram
__global__ void k_indeg(const int* __restrict__ dst, int* __restrict__ indeg) {
    int e = blockIdx.x * blockDim.x + threadIdx.x;
    if (e < N_EDGES) atomicAdd(&indeg[dst[e]], 1);
}

__global__ void k_dinv(const int* __restrict__ indeg, float* __restrict__ dinv) {
    int n = blockIdx.x * blockDim.x + threadIdx.x;
    if (n < N_NODES) dinv[n] = rsqrtf((float)(indeg[n] + 1));
}

// hierarchical scan: per-block sums
__global__ __launch_bounds__(256) void k_bsum(const int* __restrict__ indeg, int* __restrict__ bsum) {
    int b = blockIdx.x, t = threadIdx.x;
    int i = b * 256 + t;
    int v = (i < N_NODES) ? indeg[i] : 0;
#pragma unroll
    for (int m = 32; m >= 1; m >>= 1) v += __shfl_xor(v, m);
    __shared__ int s[4];
    if ((t & 63) == 0) s[t >> 6] = v;
    __syncthreads();
    if (t == 0) bsum[b] = s[0] + s[1] + s[2] + s[3];
}

// single-block scan of block sums -> exclusive bases
__global__ __launch_bounds__(256) void k_bscan(const int* __restrict__ bsum, int* __restrict__ bbase) {
    __shared__ int s[256];
    int t = threadIdx.x;
    int v = (t < NB_SCAN) ? bsum[t] : 0;
    s[t] = v;
    __syncthreads();
    for (int off = 1; off < 256; off <<= 1) {
        int tv = (t >= off) ? s[t - off] : 0;
        __syncthreads();
        s[t] += tv;
        __syncthreads();
    }
    if (t < NB_SCAN) bbase[t] = s[t] - v;
}

// per-block exclusive scan + base -> offsets & cursor
__global__ __launch_bounds__(256) void k_offsets(const int* __restrict__ indeg, const int* __restrict__ bbase,
                                                 int* __restrict__ offsets, int* __restrict__ cursor) {
    __shared__ int s[256];
    int b = blockIdx.x, t = threadIdx.x;
    int i = b * 256 + t;
    int v = (i < N_NODES) ? indeg[i] : 0;
    s[t] = v;
    __syncthreads();
    for (int off = 1; off < 256; off <<= 1) {
        int tv = (t >= off) ? s[t - off] : 0;
        __syncthreads();
        s[t] += tv;
        __syncthreads();
    }
    if (i < N_NODES) {
        int o = bbase[b] + s[t] - v;
        offsets[i] = o;
        cursor[i]  = o;
    }
}

__global__ void k_csr_fill(const int* __restrict__ src, const int* __restrict__ dst,
                           const float* __restrict__ dinv, int* __restrict__ cursor,
                           int2* __restrict__ epairs) {
    int e = blockIdx.x * blockDim.x + threadIdx.x;
    if (e >= N_EDGES) return;
    int s = src[e], d = dst[e];
    int pos = atomicAdd(&cursor[d], 1);
    float coef = dinv[s] * dinv[d];
    epairs[pos] = make_int2(s, __float_as_int(coef));
}

// counts via binary search on sorted batch (no atomics)
__global__ void k_counts_bs(const int* __restrict__ batch, int* __restrict__ counts) {
    int g = threadIdx.x;
    if (g >= N_GRAPHS) return;
    int lo = 0, hi = N_NODES;
    while (lo < hi) { int mid = (lo + hi) >> 1; if (batch[mid] < g) lo = mid + 1; else hi = mid; }
    int start = lo;
    lo = 0; hi = N_NODES;
    int g1 = g + 1;
    while (lo < hi) { int mid = (lo + hi) >> 1; if (batch[mid] < g1) lo = mid + 1; else hi = mid; }
    counts[g] = lo - start;
}

// ---------------------------------------------------------------------------
// bf16 MFMA GEMM: C[M,256] (fp32) = A_bf[M,256] @ W_bt^T  (Wbt is [n][k])
// block: 256 thr = 4 waves, tile 128M x 128N; wave = 32M x 128N
// W slice staged in 32 KB LDS per 128-k phase, chunk XOR-swizzled
__global__ __launch_bounds__(256) void k_gemm_bf(const unsigned short* __restrict__ A,
                                                 const unsigned short* __restrict__ Wbt,
                                                 float* __restrict__ C) {
    __shared__ short wlds[128 * 128];   // 32 KB
    const int t = threadIdx.x;
    const int lane = t & 63;
    const int w = t >> 6;
    const int m0 = blockIdx.x * 128;
    const int n0 = blockIdx.y * 128;

    const int lrow = lane & 15;
    const int lk = (lane >> 4) << 3;    // 0,8,16,24

    f32x4 acc[2][8];
#pragma unroll
    for (int i = 0; i < 2; ++i)
#pragma unroll
        for (int j = 0; j < 8; ++j) acc[i][j] = (f32x4){0.f, 0.f, 0.f, 0.f};

    int rowA[2];
#pragma unroll
    for (int mt = 0; mt < 2; ++mt) {
        int r = m0 + w * 32 + mt * 16 + lrow;
        rowA[mt] = (r < N_NODES) ? r : (N_NODES - 1);
    }

    for (int ph = 0; ph < 2; ++ph) {
        __syncthreads();
        // stage Wbt[n0+n][ph*128 .. +127] -> wlds, chunk-swizzled
#pragma unroll
        for (int it = 0; it < 8; ++it) {
            int cid = it * 256 + t;         // chunk id 0..2047
            int n = cid >> 4;               // 0..127
            int c = cid & 15;               // 16B chunk within row
            bf16x8 v = *(const bf16x8*)(Wbt + (size_t)(n0 + n) * 256 + ph * 128 + c * 8);
            int cs = c ^ (n & 7);
            *(bf16x8*)(wlds + (((n << 4) | cs) << 3)) = v;
        }
        __syncthreads();

#pragma unroll
        for (int ks = 0; ks < 4; ++ks) {
            int k0 = ks * 32;
            bf16x8 a[2];
#pragma unroll
            for (int mt = 0; mt < 2; ++mt)
                a[mt] = *(const bf16x8*)(A + (size_t)rowA[mt] * 256 + ph * 128 + k0 + lk);
#pragma unroll
            for (int nt = 0; nt < 8; ++nt) {
                int n = nt * 16 + lrow;
                int c = ((k0 + lk) >> 3) ^ (n & 7);
                bf16x8 b = *(const bf16x8*)(wlds + (((n << 4) | c) << 3));
                acc[0][nt] = __builtin_amdgcn_mfma_f32_16x16x32_bf16(a[0], b, acc[0][nt], 0, 0, 0);
                acc[1][nt] = __builtin_amdgcn_mfma_f32_16x16x32_bf16(a[1], b, acc[1][nt], 0, 0, 0);
            }
        }
    }

    const int srow = (lane >> 4) << 2;  // 0,4,8,12
#pragma unroll
    for (int mt = 0; mt < 2; ++mt)
#pragma unroll
        for (int nt = 0; nt < 8; ++nt)
#pragma unroll
            for (int r = 0; r < 4; ++r) {
                int row = m0 + w * 32 + mt * 16 + srow + r;
                if (row < N_NODES)
                    C[(size_t)row * 256 + n0 + nt * 16 + lrow] = acc[mt][nt][r];
            }
}

// ---------------------------------------------------------------------------
// fused gather-aggregate + self-loop + bias + LayerNorm + ReLU -> bf16 out
__global__ __launch_bounds__(256) void k_agg_ln(const float* __restrict__ h1,
                                                const int* __restrict__ offsets,
                                                const int* __restrict__ indeg,
                                                const float* __restrict__ dinv,
                                                const int2* __restrict__ epairs,
                                                const float* __restrict__ bias,
                                                const float* __restrict__ gamma,
                                                const float* __restrict__ beta,
                                                unsigned short* __restrict__ out) {
    int node = blockIdx.x * 4 + (threadIdx.x >> 6);
    int lane = threadIdx.x & 63;
    if (node >= N_NODES) return;

    const float4* h4 = (const float4*)h1;
    float di = dinv[node];
    float selfc = di * di;

    float4 v = h4[(size_t)node * 64 + lane];
    float4 acc;
    acc.x = v.x * selfc; acc.y = v.y * selfc; acc.z = v.z * selfc; acc.w = v.w * selfc;

    int beg = offsets[node];
    int end = beg + indeg[node];
    for (int i = beg; i < end; ++i) {
        int2 ep = epairs[i];
        float c = __int_as_float(ep.y);
        float4 hv = h4[(size_t)ep.x * 64 + lane];
        acc.x = fmaf(hv.x, c, acc.x);
        acc.y = fmaf(hv.y, c, acc.y);
        acc.z = fmaf(hv.z, c, acc.z);
        acc.w = fmaf(hv.w, c, acc.w);
    }

    const float4* b4 = (const float4*)bias;
    float4 bv = b4[lane];
    acc.x += bv.x; acc.y += bv.y; acc.z += bv.z; acc.w += bv.w;

    float part = acc.x + acc.y + acc.z + acc.w;
#pragma unroll
    for (int m = 32; m >= 1; m >>= 1) part += __shfl_xor(part, m);
    float mu = part * (1.0f / 256.0f);

    float dx = acc.x - mu, dy = acc.y - mu, dz = acc.z - mu, dw = acc.w - mu;
    float p2 = dx * dx + dy * dy + dz * dz + dw * dw;
#pragma unroll
    for (int m = 32; m >= 1; m >>= 1) p2 += __shfl_xor(p2, m);
    float var = p2 * (1.0f / 256.0f);
    float rs = rsqrtf(var + LN_EPS);

    const float4* g4 = (const float4*)gamma;
    const float4* be4 = (const float4*)beta;
    float4 gv = g4[lane], bev = be4[lane];
    ushort4 o;
    o.x = f2bf(fmaxf(dx * rs * gv.x + bev.x, 0.f));
    o.y = f2bf(fmaxf(dy * rs * gv.y + bev.y, 0.f));
    o.z = f2bf(fmaxf(dz * rs * gv.z + bev.z, 0.f));
    o.w = f2bf(fmaxf(dw * rs * gv.w + bev.w, 0.f));
    *((ushort4*)(out + (size_t)node * 256 + lane * 4)) = o;
}

// ---------------------------------------------------------------------------
// pooling over sorted batch: block = 128 nodes, thread = one dim
__global__ __launch_bounds__(256) void k_pool(const unsigned short* __restrict__ h,
                                              const int* __restrict__ batch,
                                              float* __restrict__ sums) {
    __shared__ int sb[128];
    int t = threadIdx.x;
    int n0 = blockIdx.x * 128;
    int cnt = N_NODES - n0; if (cnt > 128) cnt = 128;
    if (cnt <= 0) return;
    if (t < cnt) sb[t] = batch[n0 + t];
    __syncthreads();

    float acc = 0.f;
    int g = sb[0];
    for (int i = 0; i < cnt; ++i) {
        int bg = sb[i];
        if (bg != g) {
            atomicAdd(&sums[g * 256 + t], acc);
            acc = 0.f;
            g = bg;
        }
        acc += bf2f(h[(size_t)(n0 + i) * 256 + t]);
    }
    atomicAdd(&sums[g * 256 + t], acc);
}

__global__ void k_finalize(const float* __restrict__ sums, const int* __restrict__ counts,
                           float* __restrict__ out) {
    int idx = blockIdx.x * blockDim.x + threadIdx.x;
    if (idx < N_GRAPHS * 256) {
        float c = (float)counts[idx >> 8];
        out[idx] = sums[idx] / fmaxf(c, 1.f);
    }
}

// ---------------------------------------------------------------------------
extern "C" void kernel_launch(void* const* d_in, const int* in_sizes, int n_in,
                              void* d_out, int out_size, void* d_ws, size_t ws_size,
                              hipStream_t stream) {
    const float* x     = (const float*)d_in[0];
    const int*   ei    = (const int*)d_in[1];
    const int*   batch = (const int*)d_in[2];
    const float* Ws    = (const float*)d_in[3];
    const float* bs    = (const float*)d_in[4];
    const float* gammas= (const float*)d_in[5];
    const float* betas = (const float*)d_in[6];
    float* out = (float*)d_out;

    const int* src = ei;
    const int* dst = ei + N_EDGES;

    char* p = (char*)d_ws;
    float*          bufB  = (float*)p;          p += (size_t)N_NODES * D * 4;   // 51.2 MB
    unsigned short* hbf   = (unsigned short*)p; p += (size_t)N_NODES * D * 2;   // 25.6 MB
    unsigned short* Wbt   = (unsigned short*)p; p += (size_t)N_LAYERS * D * D * 2;
    int*   indeg  = (int*)p;   p += (size_t)N_NODES * 4;
    int*   offs   = (int*)p;   p += (size_t)N_NODES * 4;
    int*   cursor = (int*)p;   p += (size_t)N_NODES * 4;
    float* dinv   = (float*)p; p += (size_t)N_NODES * 4;
    int*   bsum   = (int*)p;   p += (size_t)NB_SCAN * 4;
    int*   bbase  = (int*)p;   p += (size_t)NB_SCAN * 4;
    int2*  epairs = (int2*)p;  p += (size_t)N_EDGES * 8;
    float* sums   = (float*)p; p += (size_t)N_GRAPHS * D * 4;
    int*   counts = (int*)p;   p += (size_t)N_GRAPHS * 4;

    hipMemsetAsync(indeg, 0, (size_t)N_NODES * 4, stream);
    hipMemsetAsync(sums, 0, (size_t)N_GRAPHS * D * 4, stream);

    // input conversions
    k_xtobf <<<(N_NODES * D / 8 + 255) / 256, 256, 0, stream>>>(x, hbf);
    k_wtrans<<<(N_LAYERS * D * D + 255) / 256, 256, 0, stream>>>(Ws, Wbt);

    // graph preprocessing
    k_indeg <<<(N_EDGES + 255) / 256, 256, 0, stream>>>(dst, indeg);
    k_dinv  <<<NB_SCAN, 256, 0, stream>>>(indeg, dinv);
    k_bsum  <<<NB_SCAN, 256, 0, stream>>>(indeg, bsum);
    k_bscan <<<1, 256, 0, stream>>>(bsum, bbase);
    k_offsets<<<NB_SCAN, 256, 0, stream>>>(indeg, bbase, offs, cursor);
    k_csr_fill<<<(N_EDGES + 255) / 256, 256, 0, stream>>>(src, dst, dinv, cursor, epairs);
    k_counts_bs<<<1, 64, 0, stream>>>(batch, counts);

    // 3 GCN layers
    dim3 ggrid((N_NODES + 127) / 128, 2);
    const int agg_grid = (N_NODES + 3) / 4;
    for (int l = 0; l < N_LAYERS; ++l) {
        k_gemm_bf<<<ggrid, 256, 0, stream>>>(hbf, Wbt + (size_t)l * D * D, bufB);
        k_agg_ln<<<agg_grid, 256, 0, stream>>>(bufB, offs, indeg, dinv, epairs,
                                               bs + (size_t)l * D,
                                               gammas + (size_t)l * D,
                                               betas + (size_t)l * D, hbf);
    }

    // global mean pool
    k_pool<<<(N_NODES + 127) / 128, 256, 0, stream>>>(hbf, batch, sums);
    k_finalize<<<(N_GRAPHS * 256 + 255) / 256, 256, 0, stream>>>(sums, counts, out);
}

// Round 3
// 486.395 us; speedup vs baseline: 2.2989x; 1.2565x over previous
//
#include <hip/hip_runtime.h>
#include <hip/hip_bf16.h>

#define N_NODES   50000
#define N_EDGES   800000
#define D         256
#define N_LAYERS  3
#define N_GRAPHS  64
#define LN_EPS    1e-5f
#define NB_SCAN   ((N_NODES + 255) / 256)   // 196

typedef __attribute__((ext_vector_type(8))) short bf16x8;
typedef __attribute__((ext_vector_type(4))) float f32x4;

__device__ __forceinline__ unsigned short f2bf(float f) {
    unsigned int u = __float_as_uint(f);
    unsigned int r = (u + 0x7FFFu + ((u >> 16) & 1u)) >> 16;
    return (unsigned short)r;
}
__device__ __forceinline__ float bf2f(unsigned short h) {
    return __uint_as_float(((unsigned int)h) << 16);
}

// ---------------------------------------------------------------------------
// x (fp32) -> bf16
__global__ void k_xtobf(const float* __restrict__ x, unsigned short* __restrict__ xb) {
    int gid = blockIdx.x * blockDim.x + threadIdx.x;      // one per 8 elems
    int base = gid * 8;
    if (base >= N_NODES * D) return;
    const float4* x4 = (const float4*)(x + base);
    float4 a = x4[0], b = x4[1];
    ushort4 lo, hi;
    lo.x = f2bf(a.x); lo.y = f2bf(a.y); lo.z = f2bf(a.z); lo.w = f2bf(a.w);
    hi.x = f2bf(b.x); hi.y = f2bf(b.y); hi.z = f2bf(b.z); hi.w = f2bf(b.w);
    ((ushort4*)(xb + base))[0] = lo;
    ((ushort4*)(xb + base))[1] = hi;
}

// W [l][k][n] fp32 -> Wbt [l][n][k] bf16 (transposed for MFMA loads)
__global__ void k_wtrans(const float* __restrict__ W, unsigned short* __restrict__ Wbt) {
    int gid = blockIdx.x * blockDim.x + threadIdx.x;
    if (gid >= N_LAYERS * D * D) return;
    int l = gid >> 16;
    int rem = gid & 65535;
    int n = rem >> 8;
    int k = rem & 255;
    Wbt[(size_t)l * D * D + n * D + k] = f2bf(W[(size_t)l * D * D + k * D + n]);
}

// ---------------------------------------------------------------------------
__global__ void k_indeg(const int* __restrict__ dst, int* __restrict__ indeg) {
    int e = blockIdx.x * blockDim.x + threadIdx.x;
    if (e < N_EDGES) atomicAdd(&indeg[dst[e]], 1);
}

__global__ void k_dinv(const int* __restrict__ indeg, float* __restrict__ dinv) {
    int n = blockIdx.x * blockDim.x + threadIdx.x;
    if (n < N_NODES) dinv[n] = rsqrtf((float)(indeg[n] + 1));
}

__global__ __launch_bounds__(256) void k_bsum(const int* __restrict__ indeg, int* __restrict__ bsum) {
    int b = blockIdx.x, t = threadIdx.x;
    int i = b * 256 + t;
    int v = (i < N_NODES) ? indeg[i] : 0;
#pragma unroll
    for (int m = 32; m >= 1; m >>= 1) v += __shfl_xor(v, m);
    __shared__ int s[4];
    if ((t & 63) == 0) s[t >> 6] = v;
    __syncthreads();
    if (t == 0) bsum[b] = s[0] + s[1] + s[2] + s[3];
}

__global__ __launch_bounds__(256) void k_bscan(const int* __restrict__ bsum, int* __restrict__ bbase) {
    __shared__ int s[256];
    int t = threadIdx.x;
    int v = (t < NB_SCAN) ? bsum[t] : 0;
    s[t] = v;
    __syncthreads();
    for (int off = 1; off < 256; off <<= 1) {
        int tv = (t >= off) ? s[t - off] : 0;
        __syncthreads();
        s[t] += tv;
        __syncthreads();
    }
    if (t < NB_SCAN) bbase[t] = s[t] - v;
}

__global__ __launch_bounds__(256) void k_offsets(const int* __restrict__ indeg, const int* __restrict__ bbase,
                                                 int* __restrict__ offsets, int* __restrict__ cursor) {
    __shared__ int s[256];
    int b = blockIdx.x, t = threadIdx.x;
    int i = b * 256 + t;
    int v = (i < N_NODES) ? indeg[i] : 0;
    s[t] = v;
    __syncthreads();
    for (int off = 1; off < 256; off <<= 1) {
        int tv = (t >= off) ? s[t - off] : 0;
        __syncthreads();
        s[t] += tv;
        __syncthreads();
    }
    if (i < N_NODES) {
        int o = bbase[b] + s[t] - v;
        offsets[i] = o;
        cursor[i]  = o;
    }
}

__global__ void k_csr_fill(const int* __restrict__ src, const int* __restrict__ dst,
                           const float* __restrict__ dinv, int* __restrict__ cursor,
                           int2* __restrict__ epairs) {
    int e = blockIdx.x * blockDim.x + threadIdx.x;
    if (e >= N_EDGES) return;
    int s = src[e], d = dst[e];
    int pos = atomicAdd(&cursor[d], 1);
    float coef = dinv[s] * dinv[d];
    epairs[pos] = make_int2(s, __float_as_int(coef));
}

__global__ void k_counts_bs(const int* __restrict__ batch, int* __restrict__ counts) {
    int g = threadIdx.x;
    if (g >= N_GRAPHS) return;
    int lo = 0, hi = N_NODES;
    while (lo < hi) { int mid = (lo + hi) >> 1; if (batch[mid] < g) lo = mid + 1; else hi = mid; }
    int start = lo;
    lo = 0; hi = N_NODES;
    int g1 = g + 1;
    while (lo < hi) { int mid = (lo + hi) >> 1; if (batch[mid] < g1) lo = mid + 1; else hi = mid; }
    counts[g] = lo - start;
}

// ---------------------------------------------------------------------------
// pure aggregate (bf16 gather -> fp32 acc -> bf16 out):
// one wave per node; half-wave per edge; lane owns 8 dims (16 B loads)
__global__ __launch_bounds__(256) void k_agg(const unsigned short* __restrict__ h,
                                             const int* __restrict__ offsets,
                                             const int* __restrict__ indeg,
                                             const float* __restrict__ dinv,
                                             const int2* __restrict__ epairs,
                                             unsigned short* __restrict__ outA) {
    int node = blockIdx.x * 4 + (threadIdx.x >> 6);
    int lane = threadIdx.x & 63;
    if (node >= N_NODES) return;
    int hw = lane >> 5;       // which edge of the pair
    int dl = lane & 31;       // dim-lane: dims dl*8 .. dl*8+7

    float di = dinv[node];
    float selfc = (hw == 0) ? di * di : 0.f;

    float acc[8];
    {
        bf16x8 v = *(const bf16x8*)(h + (size_t)node * 256 + dl * 8);
#pragma unroll
        for (int j = 0; j < 8; ++j) acc[j] = bf2f((unsigned short)v[j]) * selfc;
    }

    int beg = offsets[node];
    int end = beg + indeg[node];
    int i = beg + hw;
    for (; i + 2 < end; i += 4) {
        int2 e0 = epairs[i];
        int2 e1 = epairs[i + 2];
        bf16x8 v0 = *(const bf16x8*)(h + (size_t)e0.x * 256 + dl * 8);
        bf16x8 v1 = *(const bf16x8*)(h + (size_t)e1.x * 256 + dl * 8);
        float c0 = __int_as_float(e0.y);
        float c1 = __int_as_float(e1.y);
#pragma unroll
        for (int j = 0; j < 8; ++j) acc[j] = fmaf(bf2f((unsigned short)v0[j]), c0, acc[j]);
#pragma unroll
        for (int j = 0; j < 8; ++j) acc[j] = fmaf(bf2f((unsigned short)v1[j]), c1, acc[j]);
    }
    if (i < end) {
        int2 e0 = epairs[i];
        bf16x8 v0 = *(const bf16x8*)(h + (size_t)e0.x * 256 + dl * 8);
        float c0 = __int_as_float(e0.y);
#pragma unroll
        for (int j = 0; j < 8; ++j) acc[j] = fmaf(bf2f((unsigned short)v0[j]), c0, acc[j]);
    }

    // combine the two half-waves
#pragma unroll
    for (int j = 0; j < 8; ++j) acc[j] += __shfl_xor(acc[j], 32);

    if (hw == 0) {
        bf16x8 o;
#pragma unroll
        for (int j = 0; j < 8; ++j) o[j] = (short)f2bf(acc[j]);
        *(bf16x8*)(outA + (size_t)node * 256 + dl * 8) = o;
    }
}

// ---------------------------------------------------------------------------
// fused GEMM + bias + LayerNorm + ReLU -> bf16
// C[M,256] = A[M,256] @ Wbt^T ; block = 128 rows x 256 cols, 4 waves x (32 rows)
// MFMA operands swapped: mfma(Wfrag, xfrag) so reg-axis = out-dim, lane&15 = row
__global__ __launch_bounds__(256) void k_gemm_ln(const unsigned short* __restrict__ A,
                                                 const unsigned short* __restrict__ Wbt,
                                                 const float* __restrict__ bias,
                                                 const float* __restrict__ gamma,
                                                 const float* __restrict__ beta,
                                                 unsigned short* __restrict__ out) {
    const int t = threadIdx.x;
    const int lane = t & 63;
    const int w = t >> 6;
    const int lrow = lane & 15;
    const int q = lane >> 4;          // 0..3
    const int mbase = blockIdx.x * 128 + w * 32;

    f32x4 acc[2][16];
#pragma unroll
    for (int mt = 0; mt < 2; ++mt)
#pragma unroll
        for (int nt = 0; nt < 16; ++nt) acc[mt][nt] = (f32x4){0.f, 0.f, 0.f, 0.f};

    int rowA[2];
#pragma unroll
    for (int mt = 0; mt < 2; ++mt) {
        int r = mbase + mt * 16 + lrow;
        rowA[mt] = (r < N_NODES) ? r : (N_NODES - 1);
    }
    const unsigned short* a0 = A + (size_t)rowA[0] * 256 + q * 8;
    const unsigned short* a1 = A + (size_t)rowA[1] * 256 + q * 8;
    const unsigned short* wp = Wbt + (size_t)lrow * 256 + q * 8;

#pragma unroll
    for (int ks = 0; ks < 8; ++ks) {
        bf16x8 av0 = *(const bf16x8*)(a0 + ks * 32);
        bf16x8 av1 = *(const bf16x8*)(a1 + ks * 32);
#pragma unroll
        for (int nt = 0; nt < 16; ++nt) {
            bf16x8 b = *(const bf16x8*)(wp + (size_t)nt * 16 * 256 + ks * 32);
            acc[0][nt] = __builtin_amdgcn_mfma_f32_16x16x32_bf16(b, av0, acc[0][nt], 0, 0, 0);
            acc[1][nt] = __builtin_amdgcn_mfma_f32_16x16x32_bf16(b, av1, acc[1][nt], 0, 0, 0);
        }
    }

    // epilogue: bias -> LN stats (row = mbase+mt*16+lrow; n = nt*16+q*4+r) -> relu -> bf16
    const float4* bias4 = (const float4*)bias;
    const float4* g4 = (const float4*)gamma;
    const float4* be4 = (const float4*)beta;

#pragma unroll
    for (int mt = 0; mt < 2; ++mt) {
        float s = 0.f, s2 = 0.f;
#pragma unroll
        for (int nt = 0; nt < 16; ++nt) {
            float4 bv = bias4[nt * 4 + q];
#pragma unroll
            for (int r = 0; r < 4; ++r) {
                float v = acc[mt][nt][r] + ((const float*)&bv)[r];
                acc[mt][nt][r] = v;
                s += v;
                s2 += v * v;
            }
        }
        s  += __shfl_xor(s, 16);  s  += __shfl_xor(s, 32);
        s2 += __shfl_xor(s2, 16); s2 += __shfl_xor(s2, 32);
        float mu = s * (1.0f / 256.0f);
        float var = s2 * (1.0f / 256.0f) - mu * mu;
        float rs = rsqrtf(var + LN_EPS);

        int row = mbase + mt * 16 + lrow;
        if (row < N_NODES) {
#pragma unroll
            for (int nt = 0; nt < 16; ++nt) {
                float4 gv = g4[nt * 4 + q];
                float4 bev = be4[nt * 4 + q];
                ushort4 o;
                float v0 = fmaxf((acc[mt][nt][0] - mu) * rs * gv.x + bev.x, 0.f);
                float v1 = fmaxf((acc[mt][nt][1] - mu) * rs * gv.y + bev.y, 0.f);
                float v2 = fmaxf((acc[mt][nt][2] - mu) * rs * gv.z + bev.z, 0.f);
                float v3 = fmaxf((acc[mt][nt][3] - mu) * rs * gv.w + bev.w, 0.f);
                o.x = f2bf(v0); o.y = f2bf(v1); o.z = f2bf(v2); o.w = f2bf(v3);
                *(ushort4*)(out + (size_t)row * 256 + nt * 16 + q * 4) = o;
            }
        }
    }
}

// ---------------------------------------------------------------------------
__global__ __launch_bounds__(256) void k_pool(const unsigned short* __restrict__ h,
                                              const int* __restrict__ batch,
                                              float* __restrict__ sums) {
    __shared__ int sb[128];
    int t = threadIdx.x;
    int n0 = blockIdx.x * 128;
    int cnt = N_NODES - n0; if (cnt > 128) cnt = 128;
    if (cnt <= 0) return;
    if (t < cnt) sb[t] = batch[n0 + t];
    __syncthreads();

    float acc = 0.f;
    int g = sb[0];
    for (int i = 0; i < cnt; ++i) {
        int bg = sb[i];
        if (bg != g) {
            atomicAdd(&sums[g * 256 + t], acc);
            acc = 0.f;
            g = bg;
        }
        acc += bf2f(h[(size_t)(n0 + i) * 256 + t]);
    }
    atomicAdd(&sums[g * 256 + t], acc);
}

__global__ void k_finalize(const float* __restrict__ sums, const int* __restrict__ counts,
                           float* __restrict__ out) {
    int idx = blockIdx.x * blockDim.x + threadIdx.x;
    if (idx < N_GRAPHS * 256) {
        float c = (float)counts[idx >> 8];
        out[idx] = sums[idx] / fmaxf(c, 1.f);
    }
}

// ---------------------------------------------------------------------------
extern "C" void kernel_launch(void* const* d_in, const int* in_sizes, int n_in,
                              void* d_out, int out_size, void* d_ws, size_t ws_size,
                              hipStream_t stream) {
    const float* x     = (const float*)d_in[0];
    const int*   ei    = (const int*)d_in[1];
    const int*   batch = (const int*)d_in[2];
    const float* Ws    = (const float*)d_in[3];
    const float* bs    = (const float*)d_in[4];
    const float* gammas= (const float*)d_in[5];
    const float* betas = (const float*)d_in[6];
    float* out = (float*)d_out;

    const int* src = ei;
    const int* dst = ei + N_EDGES;

    char* p = (char*)d_ws;
    unsigned short* hbf   = (unsigned short*)p; p += (size_t)N_NODES * D * 2;   // 25.6 MB
    unsigned short* aggx  = (unsigned short*)p; p += (size_t)N_NODES * D * 2;   // 25.6 MB
    unsigned short* Wbt   = (unsigned short*)p; p += (size_t)N_LAYERS * D * D * 2;
    int*   indeg  = (int*)p;   p += (size_t)N_NODES * 4;
    int*   offs   = (int*)p;   p += (size_t)N_NODES * 4;
    int*   cursor = (int*)p;   p += (size_t)N_NODES * 4;
    float* dinv   = (float*)p; p += (size_t)N_NODES * 4;
    int*   bsum   = (int*)p;   p += (size_t)NB_SCAN * 4;
    int*   bbase  = (int*)p;   p += (size_t)NB_SCAN * 4;
    int2*  epairs = (int2*)p;  p += (size_t)N_EDGES * 8;
    float* sums   = (float*)p; p += (size_t)N_GRAPHS * D * 4;
    int*   counts = (int*)p;   p += (size_t)N_GRAPHS * 4;

    hipMemsetAsync(indeg, 0, (size_t)N_NODES * 4, stream);
    hipMemsetAsync(sums, 0, (size_t)N_GRAPHS * D * 4, stream);

    // input conversions
    k_xtobf <<<(N_NODES * D / 8 + 255) / 256, 256, 0, stream>>>(x, hbf);
    k_wtrans<<<(N_LAYERS * D * D + 255) / 256, 256, 0, stream>>>(Ws, Wbt);

    // graph preprocessing
    k_indeg <<<(N_EDGES + 255) / 256, 256, 0, stream>>>(dst, indeg);
    k_dinv  <<<NB_SCAN, 256, 0, stream>>>(indeg, dinv);
    k_bsum  <<<NB_SCAN, 256, 0, stream>>>(indeg, bsum);
    k_bscan <<<1, 256, 0, stream>>>(bsum, bbase);
    k_offsets<<<NB_SCAN, 256, 0, stream>>>(indeg, bbase, offs, cursor);
    k_csr_fill<<<(N_EDGES + 255) / 256, 256, 0, stream>>>(src, dst, dinv, cursor, epairs);
    k_counts_bs<<<1, 64, 0, stream>>>(batch, counts);

    // 3 GCN layers: aggregate-first (agg(h)W == agg(hW)), GEMM fused with bias+LN+ReLU
    const int agg_grid  = (N_NODES + 3) / 4;
    const int gemm_grid = (N_NODES + 127) / 128;
    for (int l = 0; l < N_LAYERS; ++l) {
        k_agg<<<agg_grid, 256, 0, stream>>>(hbf, offs, indeg, dinv, epairs, aggx);
        k_gemm_ln<<<gemm_grid, 256, 0, stream>>>(aggx, Wbt + (size_t)l * D * D,
                                                 bs + (size_t)l * D,
                                                 gammas + (size_t)l * D,
                                                 betas + (size_t)l * D, hbf);
    }

    // global mean pool
    k_pool<<<(N_NODES + 127) / 128, 256, 0, stream>>>(hbf, batch, sums);
    k_finalize<<<(N_GRAPHS * 256 + 255) / 256, 256, 0, stream>>>(sums, counts, out);
}